// Round 15
// baseline (1830.253 us; speedup 1.0000x reference)
//
#include <hip/hip_runtime.h>
#include <hip/hip_bf16.h>
#include <math.h>

#define GH 721
#define GW 1440
#define C_IN 78
#define NNODES 5882
#define KNEIGH 128
#define M_TOTAL (NNODES * KNEIGH)   // 752896
#define TM 64
#define TILES 4
#define NBLOCKS (M_TOTAL / (TM * TILES))   // 2941

typedef __attribute__((ext_vector_type(8))) short bf16x8;
typedef __attribute__((ext_vector_type(4))) float f32x4;

__device__ __forceinline__ unsigned short f2bf(float x) {
    __hip_bfloat16 b = __float2bfloat16(x);
    union { __hip_bfloat16 h; unsigned short u; } cv; cv.h = b; return cv.u;
}

// ---------------- prep kernel (unchanged from R11) ----------------
__global__ void prep_kernel(const float* __restrict__ W1, const float* __restrict__ W2,
                            const float* __restrict__ means, const float* __restrict__ stds,
                            const float* __restrict__ b1, const float* __restrict__ lnS,
                            const float* __restrict__ lnO, const float* __restrict__ b2,
                            unsigned short* __restrict__ bp1, unsigned short* __restrict__ bp2,
                            float* __restrict__ latT, float* __restrict__ lonT,
                            float* __restrict__ b1p, float* __restrict__ K1,
                            float* __restrict__ K2)
{
    const int NB1 = 3 * 4 * 256 * 8;   // 24576
    const int NB2 = 8 * 4 * 256 * 8;   // 65536
    const int NTOT = NB1 + NB2 + GH + GW + 256;
    for (int e = blockIdx.x * blockDim.x + threadIdx.x; e < NTOT;
         e += gridDim.x * blockDim.x) {
        if (e < NB1) {
            int j = e & 7, c = (e >> 3) & 255, o = (e >> 11) & 3, s = e >> 13;
            int k = s * 32 + o * 8 + j;
            float v = 0.f;
            if (k < 82) v = W1[k * 256 + c] / (stds[k] + 1e-7f);
            bp1[e] = f2bf(v);
        } else if (e < NB1 + NB2) {
            int t = e - NB1;
            int j = t & 7, c = (t >> 3) & 255, o = (t >> 11) & 3, s = t >> 13;
            int k = s * 32 + o * 8 + j;
            bp2[t] = f2bf(W2[k * 256 + c] * lnS[k]);
        } else if (e < NB1 + NB2 + GH) {
            int h = e - NB1 - NB2;
            float r = (-90.f + 0.25f * (float)h) * 0.017453292519943295f;
            latT[2 * h]     = sinf(r);
            latT[2 * h + 1] = cosf(r);
        } else if (e < NB1 + NB2 + GH + GW) {
            int w = e - NB1 - NB2 - GH;
            float r = ((float)w * (360.f / 1439.f)) * 0.017453292519943295f;
            lonT[2 * w]     = sinf(r);
            lonT[2 * w + 1] = cosf(r);
        } else {
            int c = e - NB1 - NB2 - GH - GW;   // output/hidden column 0..255
            float acc = b1[c];
            #pragma unroll 1
            for (int k = 0; k < 86; ++k) {
                float inv = 1.f / (stds[k] + 1e-7f);
                float w = W1[k * 256 + c] * inv;
                acc -= means[k] * w;
                if (k == 82) acc += 0.5f * w;   // day-of-year channel, raw value 0.5
            }
            b1p[c] = acc;
            float k1 = 0.f, k2 = 0.f;
            #pragma unroll 1
            for (int k = 0; k < 256; ++k) {
                float w = W2[k * 256 + c];
                k1 += lnS[k] * w;
                k2 += lnO[k] * w;
            }
            K1[c] = k1;
            K2[c] = k2 + b2[c];
        }
    }
}

// ---------------- fused kernel: 4 pipelined 64-row tiles per block ----------------
// R12's schedule, de-bloated: tile loop NOT unrolled (R12's full unroll entangled
// 4 tiles' live ranges -> spill), no lambdas. Held across GEMM1: g[5]+tl+tl2 = 14
// regs. Budget: 32 acc(AGPR) + ~90 arch < 128 unified cap -> 16 waves/CU, no spill.
__global__ __launch_bounds__(512, 4)
void fused_kernel(const float* __restrict__ var_grid, const int* __restrict__ idxs,
                  const unsigned short* __restrict__ bp1, const unsigned short* __restrict__ bp2,
                  const float* __restrict__ latT, const float* __restrict__ lonT,
                  const float* __restrict__ b1p, const float* __restrict__ K1,
                  const float* __restrict__ K2,
                  float* __restrict__ out)
{
    __shared__ __align__(16) unsigned short x_lds[2][TM][104];   // 26.6 KB dbuf
    __shared__ __align__(16) unsigned short h_lds[TM * 256];     // 32 KB
    __shared__ float red[2][2][4][TM];                           // 4 KB

    // Bijective XCD-aware swizzle (nwg=2941, q=367, r=5)
    const int q_ = 367, r_ = 5;
    const int xcd = blockIdx.x & 7;
    const int ii  = blockIdx.x >> 3;
    const int swz = (xcd < r_ ? xcd * (q_ + 1) : r_ * (q_ + 1) + (xcd - r_) * q_) + ii;

    const int tid  = threadIdx.x;
    const int lane = tid & 63;
    const int wave = tid >> 6;       // 0..7
    const int wr   = wave >> 2;      // 0..1  row half (32 rows)
    const int wc   = wave & 3;       // 0..3  col quarter (64 cols)
    const int l15  = lane & 15;
    const int lg   = lane >> 4;      // 0..3
    const int wbase = wc * 64;
    const int rbase = wr * 32;
    const long block0 = (long)swz * (TM * TILES);

    const int grow = tid >> 3, gp = tid & 7;   // gather: 8 lanes/row, rows 0..63

    float2 g[5], tl, tl2;

    // ---- prologue: gather tile 0 -> regs -> pack ----
    {
        const int idx = idxs[block0 + grow];
        const int hh = idx / GW;
        const int ww = idx - hh * GW;
        const float* src = var_grid + (long)idx * C_IN;
        #pragma unroll
        for (int u = 0; u < 5; ++u) {
            const int q = gp + 8 * u;
            if (q < 39) g[u] = *(const float2*)(src + 2 * q);
        }
        tl.x  = latT[2 * hh]; tl.y  = latT[2 * hh + 1];
        tl2.x = lonT[2 * ww]; tl2.y = lonT[2 * ww + 1];
    }
    float b1v[4];
    #pragma unroll
    for (int nf = 0; nf < 4; ++nf) b1v[nf] = b1p[wbase + nf * 16 + l15];
    {
        unsigned int* xrow = (unsigned int*)&x_lds[0][grow][0];
        #pragma unroll
        for (int u = 0; u < 6; ++u) {
            const int q = gp + 8 * u;
            float v0, v1;
            if (q < 39)       { v0 = g[u].x; v1 = g[u].y; }
            else if (q == 39) { v0 = tl.x;  v1 = tl.y; }
            else if (q == 40) { v0 = tl2.x; v1 = tl2.y; }
            else              { v0 = 0.f; v1 = 0.f; }
            xrow[q] = ((unsigned int)f2bf(v1) << 16) | (unsigned int)f2bf(v0);
        }
    }

    #pragma unroll 1
    for (int t = 0; t < TILES; ++t) {
        __syncthreads();   // x[t&1] visible; prev tile's h/red reads complete

        // ---- issue gather(t+1): loads fly under GEMM1 + stats ----
        if (t + 1 < TILES) {
            const int idx = idxs[block0 + (t + 1) * TM + grow];
            const int hh = idx / GW;
            const int ww = idx - hh * GW;
            const float* src = var_grid + (long)idx * C_IN;
            #pragma unroll
            for (int u = 0; u < 5; ++u) {
                const int q = gp + 8 * u;
                if (q < 39) g[u] = *(const float2*)(src + 2 * q);
            }
            tl.x  = latT[2 * hh]; tl.y  = latT[2 * hh + 1];
            tl2.x = lonT[2 * ww]; tl2.y = lonT[2 * ww + 1];
        }

        // ---- GEMM1: x[64x96] @ W1'[96x256] ----
        f32x4 acc[2][4];
        #pragma unroll
        for (int mf = 0; mf < 2; ++mf)
            #pragma unroll
            for (int nf = 0; nf < 4; ++nf) acc[mf][nf] = (f32x4){0.f, 0.f, 0.f, 0.f};

        #pragma unroll
        for (int s = 0; s < 3; ++s) {
            bf16x8 af[2], bw[4];
            #pragma unroll
            for (int nf = 0; nf < 4; ++nf)
                bw[nf] = *(const bf16x8*)(bp1 + ((size_t)((s * 4 + lg) * 256) + wbase + nf * 16 + l15) * 8);
            #pragma unroll
            for (int mf = 0; mf < 2; ++mf)
                af[mf] = *(const bf16x8*)&x_lds[t & 1][rbase + mf * 16 + l15][s * 32 + lg * 8];
            #pragma unroll
            for (int mf = 0; mf < 2; ++mf)
                #pragma unroll
                for (int nf = 0; nf < 4; ++nf)
                    acc[mf][nf] = __builtin_amdgcn_mfma_f32_16x16x32_bf16(af[mf], bw[nf], acc[mf][nf], 0, 0, 0);
        }

        // ---- bias + ReLU -> h (bf16, swizzled) + row-stat partials ----
        float sm[2][4], sq[2][4];
        #pragma unroll
        for (int mf = 0; mf < 2; ++mf)
            #pragma unroll
            for (int i = 0; i < 4; ++i) { sm[mf][i] = 0.f; sq[mf][i] = 0.f; }

        #pragma unroll
        for (int mf = 0; mf < 2; ++mf)
            #pragma unroll
            for (int nf = 0; nf < 4; ++nf)
                #pragma unroll
                for (int i = 0; i < 4; ++i) {
                    float v = fmaxf(acc[mf][nf][i] + b1v[nf], 0.f);
                    sm[mf][i] += v;
                    sq[mf][i] += v * v;
                    int row = rbase + mf * 16 + lg * 4 + i;
                    int col = wbase + nf * 16 + l15;
                    unsigned off = (unsigned)(row * 512 + col * 2);
                    off ^= (unsigned)((row & 7) << 4);
                    *(unsigned short*)((char*)h_lds + off) = f2bf(v);
                }

        #pragma unroll
        for (int m = 1; m < 16; m <<= 1)
            #pragma unroll
            for (int mf = 0; mf < 2; ++mf)
                #pragma unroll
                for (int i = 0; i < 4; ++i) {
                    sm[mf][i] += __shfl_xor(sm[mf][i], m, 64);
                    sq[mf][i] += __shfl_xor(sq[mf][i], m, 64);
                }

        if (l15 == 0) {
            #pragma unroll
            for (int mf = 0; mf < 2; ++mf)
                #pragma unroll
                for (int i = 0; i < 4; ++i) {
                    int row = rbase + mf * 16 + lg * 4 + i;
                    red[t & 1][0][wc][row] = sm[mf][i];
                    red[t & 1][1][wc][row] = sq[mf][i];
                }
        }

        // ---- pack tile t+1 (waits loads; they had GEMM1+stats to land) ----
        if (t + 1 < TILES) {
            unsigned int* xrow = (unsigned int*)&x_lds[(t + 1) & 1][grow][0];
            #pragma unroll
            for (int u = 0; u < 6; ++u) {
                const int q = gp + 8 * u;
                float v0, v1;
                if (q < 39)       { v0 = g[u].x; v1 = g[u].y; }
                else if (q == 39) { v0 = tl.x;  v1 = tl.y; }
                else if (q == 40) { v0 = tl2.x; v1 = tl2.y; }
                else              { v0 = 0.f; v1 = 0.f; }
                xrow[q] = ((unsigned int)f2bf(v1) << 16) | (unsigned int)f2bf(v0);
            }
        }

        __syncthreads();   // h, red, x[t+1] visible

        // ---- GEMM2: h[64x256] @ W2'[256x256] ----
        #pragma unroll
        for (int mf = 0; mf < 2; ++mf)
            #pragma unroll
            for (int nf = 0; nf < 4; ++nf) acc[mf][nf] = (f32x4){0.f, 0.f, 0.f, 0.f};

        #pragma unroll
        for (int s = 0; s < 8; ++s) {
            bf16x8 af[2], bw[4];
            #pragma unroll
            for (int nf = 0; nf < 4; ++nf)
                bw[nf] = *(const bf16x8*)(bp2 + ((size_t)((s * 4 + lg) * 256) + wbase + nf * 16 + l15) * 8);
            #pragma unroll
            for (int mf = 0; mf < 2; ++mf) {
                int row = rbase + mf * 16 + l15;
                unsigned off = (unsigned)(row * 512 + (s * 32 + lg * 8) * 2);
                off ^= (unsigned)((row & 7) << 4);
                af[mf] = *(const bf16x8*)((char*)h_lds + off);
            }
            #pragma unroll
            for (int mf = 0; mf < 2; ++mf)
                #pragma unroll
                for (int nf = 0; nf < 4; ++nf)
                    acc[mf][nf] = __builtin_amdgcn_mfma_f32_16x16x32_bf16(af[mf], bw[nf], acc[mf][nf], 0, 0, 0);
        }

        // ---- epilogue: LN algebraic; direct plain stores ----
        float K1v[4], K2v[4];
        #pragma unroll
        for (int nf = 0; nf < 4; ++nf) {
            int col = wbase + nf * 16 + l15;
            K1v[nf] = K1[col]; K2v[nf] = K2[col];
        }
        #pragma unroll
        for (int mf = 0; mf < 2; ++mf)
            #pragma unroll
            for (int i = 0; i < 4; ++i) {
                int row = rbase + mf * 16 + lg * 4 + i;
                float tot = red[t & 1][0][0][row] + red[t & 1][0][1][row]
                          + red[t & 1][0][2][row] + red[t & 1][0][3][row];
                float tq  = red[t & 1][1][0][row] + red[t & 1][1][1][row]
                          + red[t & 1][1][2][row] + red[t & 1][1][3][row];
                float mean = tot * (1.f / 256.f);
                float var  = tq * (1.f / 256.f) - mean * mean;
                float rs = rsqrtf(var + 1e-5f);
                long row_g = block0 + t * TM + row;
                float* po = out + row_g * 256 + wbase;
                #pragma unroll
                for (int nf = 0; nf < 4; ++nf)
                    po[nf * 16 + l15] = rs * (acc[mf][nf][i] - mean * K1v[nf]) + K2v[nf];
            }
    }
}

extern "C" void kernel_launch(void* const* d_in, const int* in_sizes, int n_in,
                              void* d_out, int out_size, void* d_ws, size_t ws_size,
                              hipStream_t stream) {
    const float* var_grid = (const float*)d_in[0];
    const int*   idxs     = (const int*)d_in[1];
    const float* means    = (const float*)d_in[2];
    const float* stds     = (const float*)d_in[3];
    const float* W1       = (const float*)d_in[4];
    const float* b1       = (const float*)d_in[5];
    const float* lnS      = (const float*)d_in[6];
    const float* lnO      = (const float*)d_in[7];
    const float* W2       = (const float*)d_in[8];
    const float* b2       = (const float*)d_in[9];
    float* out = (float*)d_out;

    char* ws = (char*)d_ws;
    unsigned short* bp1 = (unsigned short*)ws;               // 49152 B
    unsigned short* bp2 = (unsigned short*)(ws + 49152);     // 131072 B -> 180224
    float* latT = (float*)(ws + 180224);                     // 5768 B
    float* lonT = (float*)(ws + 186000);                     // 11520 B
    float* b1p  = (float*)(ws + 197520);                     // 1024 B
    float* K1   = (float*)(ws + 198544);                     // 1024 B
    float* K2   = (float*)(ws + 199568);                     // 1024 B (end 200592)

    prep_kernel<<<362, 256, 0, stream>>>(W1, W2, means, stds, b1, lnS, lnO, b2,
                                         bp1, bp2, latT, lonT, b1p, K1, K2);
    fused_kernel<<<NBLOCKS, 512, 0, stream>>>(var_grid, idxs, bp1, bp2, latT, lonT,
                                              b1p, K1, K2, out);
}

// Round 16
// 525.437 us; speedup vs baseline: 3.4833x; 3.4833x over previous
//
#include <hip/hip_runtime.h>
#include <hip/hip_bf16.h>
#include <math.h>

#define GH 721
#define GW 1440
#define C_IN 78
#define NNODES 5882
#define KNEIGH 128
#define M_TOTAL (NNODES * KNEIGH)   // 752896

typedef __attribute__((ext_vector_type(8))) short bf16x8;
typedef __attribute__((ext_vector_type(4))) float f32x4;

__device__ __forceinline__ unsigned short f2bf(float x) {
    __hip_bfloat16 b = __float2bfloat16(x);
    union { __hip_bfloat16 h; unsigned short u; } cv; cv.h = b; return cv.u;
}

// ---------------- prep kernel (unchanged from R11) ----------------
__global__ void prep_kernel(const float* __restrict__ W1, const float* __restrict__ W2,
                            const float* __restrict__ means, const float* __restrict__ stds,
                            const float* __restrict__ b1, const float* __restrict__ lnS,
                            const float* __restrict__ lnO, const float* __restrict__ b2,
                            unsigned short* __restrict__ bp1, unsigned short* __restrict__ bp2,
                            float* __restrict__ latT, float* __restrict__ lonT,
                            float* __restrict__ b1p, float* __restrict__ K1,
                            float* __restrict__ K2)
{
    const int NB1 = 3 * 4 * 256 * 8;   // 24576
    const int NB2 = 8 * 4 * 256 * 8;   // 65536
    const int NTOT = NB1 + NB2 + GH + GW + 256;
    for (int e = blockIdx.x * blockDim.x + threadIdx.x; e < NTOT;
         e += gridDim.x * blockDim.x) {
        if (e < NB1) {
            int j = e & 7, c = (e >> 3) & 255, o = (e >> 11) & 3, s = e >> 13;
            int k = s * 32 + o * 8 + j;
            float v = 0.f;
            if (k < 82) v = W1[k * 256 + c] / (stds[k] + 1e-7f);
            bp1[e] = f2bf(v);
        } else if (e < NB1 + NB2) {
            int t = e - NB1;
            int j = t & 7, c = (t >> 3) & 255, o = (t >> 11) & 3, s = t >> 13;
            int k = s * 32 + o * 8 + j;
            bp2[t] = f2bf(W2[k * 256 + c] * lnS[k]);
        } else if (e < NB1 + NB2 + GH) {
            int h = e - NB1 - NB2;
            float r = (-90.f + 0.25f * (float)h) * 0.017453292519943295f;
            latT[2 * h]     = sinf(r);
            latT[2 * h + 1] = cosf(r);
        } else if (e < NB1 + NB2 + GH + GW) {
            int w = e - NB1 - NB2 - GH;
            float r = ((float)w * (360.f / 1439.f)) * 0.017453292519943295f;
            lonT[2 * w]     = sinf(r);
            lonT[2 * w + 1] = cosf(r);
        } else {
            int c = e - NB1 - NB2 - GH - GW;   // output/hidden column 0..255
            float acc = b1[c];
            #pragma unroll 1
            for (int k = 0; k < 86; ++k) {
                float inv = 1.f / (stds[k] + 1e-7f);
                float w = W1[k * 256 + c] * inv;
                acc -= means[k] * w;
                if (k == 82) acc += 0.5f * w;   // day-of-year channel, raw value 0.5
            }
            b1p[c] = acc;
            float k1 = 0.f, k2 = 0.f;
            #pragma unroll 1
            for (int k = 0; k < 256; ++k) {
                float w = W2[k * 256 + c];
                k1 += lnS[k] * w;
                k2 += lnO[k] * w;
            }
            K1[c] = k1;
            K2[c] = k2 + b2[c];
        }
    }
}

// ---------------- G: gather -> xbuf[M][96] bf16 ----------------
// Pure-memory kernel: random row reads, fully-coalesced 16-B packed writes.
// Runs at max TLP; removes the 900-cyc gather stall from the MLP critical path.
__global__ __launch_bounds__(256)
void gather_kernel(const float* __restrict__ var_grid, const int* __restrict__ idxs,
                   const float* __restrict__ latT, const float* __restrict__ lonT,
                   unsigned short* __restrict__ xbuf)
{
    const long NU = (long)M_TOTAL * 12;          // one unit = 8 bf16 = 16 B out
    const int b = blockIdx.x;
    const int swz = (b & 7) * 256 + (b >> 3);    // XCD swizzle, nwg=2048
    for (long unit = (long)swz * 256 + threadIdx.x; unit < NU;
         unit += (long)gridDim.x * 256) {
        const int row = (int)(unit / 12);
        const int u   = (int)(unit - (long)row * 12);
        const int idx = idxs[row];
        const float* src = var_grid + (long)idx * C_IN;
        float v[8];
        if (u < 9) {
            #pragma unroll
            for (int j = 0; j < 4; ++j) {
                float2 t = *(const float2*)(src + u * 8 + 2 * j);
                v[2 * j] = t.x; v[2 * j + 1] = t.y;
            }
        } else if (u == 9) {                     // ch 72..77 grid, 78..79 lat
            #pragma unroll
            for (int j = 0; j < 3; ++j) {
                float2 t = *(const float2*)(src + 72 + 2 * j);
                v[2 * j] = t.x; v[2 * j + 1] = t.y;
            }
            int hh = idx / GW;
            v[6] = latT[2 * hh]; v[7] = latT[2 * hh + 1];
        } else if (u == 10) {                    // ch 80..81 lon, 82..87 folded->0
            int hh = idx / GW;
            int ww = idx - hh * GW;
            v[0] = lonT[2 * ww]; v[1] = lonT[2 * ww + 1];
            #pragma unroll
            for (int j = 2; j < 8; ++j) v[j] = 0.f;
        } else {                                 // ch 88..95 pad
            #pragma unroll
            for (int j = 0; j < 8; ++j) v[j] = 0.f;
        }
        uint4 o;
        o.x = ((unsigned)f2bf(v[1]) << 16) | f2bf(v[0]);
        o.y = ((unsigned)f2bf(v[3]) << 16) | f2bf(v[2]);
        o.z = ((unsigned)f2bf(v[5]) << 16) | f2bf(v[4]);
        o.w = ((unsigned)f2bf(v[7]) << 16) | f2bf(v[6]);
        *(uint4*)(xbuf + (size_t)row * 96 + u * 8) = o;
    }
}

// ---------------- F: streaming MLP xbuf -> out ----------------
// No gather, no idxs, no pack. GEMM1 A-fragments read directly from xbuf
// (16-B aligned; tile L2-resident). ONE barrier per block.
__global__ __launch_bounds__(512, 4)
void mlp_kernel(const unsigned short* __restrict__ xbuf,
                const unsigned short* __restrict__ bp1, const unsigned short* __restrict__ bp2,
                const float* __restrict__ b1p, const float* __restrict__ K1,
                const float* __restrict__ K2,
                float* __restrict__ out)
{
    __shared__ __align__(16) unsigned short h_lds[64 * 256];   // 32 KB, XOR-swizzled
    __shared__ float red[2][4][64];                            // 2 KB

    const int tid  = threadIdx.x;
    const int lane = tid & 63;
    const int wave = tid >> 6;       // 0..7
    const int wr   = wave >> 2;      // 0..1
    const int wc   = wave & 3;       // 0..3
    const int l15  = lane & 15;
    const int lg   = lane >> 4;      // 0..3
    const int wbase = wc * 64;
    const int rbase = wr * 32;
    const long block0 = (long)blockIdx.x * 64;

    float b1v[4];
    #pragma unroll
    for (int nf = 0; nf < 4; ++nf) b1v[nf] = b1p[wbase + nf * 16 + l15];

    // ---- GEMM1: x[64x96] (global, linear) @ W1'[96x256] ----
    f32x4 acc[2][4];
    #pragma unroll
    for (int mf = 0; mf < 2; ++mf)
        #pragma unroll
        for (int nf = 0; nf < 4; ++nf) acc[mf][nf] = (f32x4){0.f, 0.f, 0.f, 0.f};

    #pragma unroll
    for (int s = 0; s < 3; ++s) {
        bf16x8 af[2], bw[4];
        #pragma unroll
        for (int nf = 0; nf < 4; ++nf)
            bw[nf] = *(const bf16x8*)(bp1 + ((size_t)((s * 4 + lg) * 256) + wbase + nf * 16 + l15) * 8);
        #pragma unroll
        for (int mf = 0; mf < 2; ++mf)
            af[mf] = *(const bf16x8*)(xbuf + (size_t)(block0 + rbase + mf * 16 + l15) * 96
                                            + s * 32 + lg * 8);
        #pragma unroll
        for (int mf = 0; mf < 2; ++mf)
            #pragma unroll
            for (int nf = 0; nf < 4; ++nf)
                acc[mf][nf] = __builtin_amdgcn_mfma_f32_16x16x32_bf16(af[mf], bw[nf], acc[mf][nf], 0, 0, 0);
    }

    // ---- bias + ReLU -> h (bf16, swizzled) + row-stat partials ----
    float sm[2][4], sq[2][4];
    #pragma unroll
    for (int mf = 0; mf < 2; ++mf)
        #pragma unroll
        for (int i = 0; i < 4; ++i) { sm[mf][i] = 0.f; sq[mf][i] = 0.f; }

    #pragma unroll
    for (int mf = 0; mf < 2; ++mf)
        #pragma unroll
        for (int nf = 0; nf < 4; ++nf)
            #pragma unroll
            for (int i = 0; i < 4; ++i) {
                float v = fmaxf(acc[mf][nf][i] + b1v[nf], 0.f);
                sm[mf][i] += v;
                sq[mf][i] += v * v;
                int row = rbase + mf * 16 + lg * 4 + i;
                int col = wbase + nf * 16 + l15;
                unsigned off = (unsigned)(row * 512 + col * 2);
                off ^= (unsigned)((row & 7) << 4);
                *(unsigned short*)((char*)h_lds + off) = f2bf(v);
            }

    #pragma unroll
    for (int m = 1; m < 16; m <<= 1)
        #pragma unroll
        for (int mf = 0; mf < 2; ++mf)
            #pragma unroll
            for (int i = 0; i < 4; ++i) {
                sm[mf][i] += __shfl_xor(sm[mf][i], m, 64);
                sq[mf][i] += __shfl_xor(sq[mf][i], m, 64);
            }

    if (l15 == 0) {
        #pragma unroll
        for (int mf = 0; mf < 2; ++mf)
            #pragma unroll
            for (int i = 0; i < 4; ++i) {
                int row = rbase + mf * 16 + lg * 4 + i;
                red[0][wc][row] = sm[mf][i];
                red[1][wc][row] = sq[mf][i];
            }
    }
    __syncthreads();   // the ONLY barrier: h + red visible

    // ---- GEMM2: h[64x256] @ W2'[256x256] ----
    #pragma unroll
    for (int mf = 0; mf < 2; ++mf)
        #pragma unroll
        for (int nf = 0; nf < 4; ++nf) acc[mf][nf] = (f32x4){0.f, 0.f, 0.f, 0.f};

    #pragma unroll
    for (int s = 0; s < 8; ++s) {
        bf16x8 af[2], bw[4];
        #pragma unroll
        for (int nf = 0; nf < 4; ++nf)
            bw[nf] = *(const bf16x8*)(bp2 + ((size_t)((s * 4 + lg) * 256) + wbase + nf * 16 + l15) * 8);
        #pragma unroll
        for (int mf = 0; mf < 2; ++mf) {
            int row = rbase + mf * 16 + l15;
            unsigned off = (unsigned)(row * 512 + (s * 32 + lg * 8) * 2);
            off ^= (unsigned)((row & 7) << 4);
            af[mf] = *(const bf16x8*)((char*)h_lds + off);
        }
        #pragma unroll
        for (int mf = 0; mf < 2; ++mf)
            #pragma unroll
            for (int nf = 0; nf < 4; ++nf)
                acc[mf][nf] = __builtin_amdgcn_mfma_f32_16x16x32_bf16(af[mf], bw[nf], acc[mf][nf], 0, 0, 0);
    }

    // ---- epilogue: LN algebraic; direct plain stores ----
    float K1v[4], K2v[4];
    #pragma unroll
    for (int nf = 0; nf < 4; ++nf) {
        int col = wbase + nf * 16 + l15;
        K1v[nf] = K1[col]; K2v[nf] = K2[col];
    }
    #pragma unroll
    for (int mf = 0; mf < 2; ++mf)
        #pragma unroll
        for (int i = 0; i < 4; ++i) {
            int row = rbase + mf * 16 + lg * 4 + i;
            float tot = red[0][0][row] + red[0][1][row] + red[0][2][row] + red[0][3][row];
            float tq  = red[1][0][row] + red[1][1][row] + red[1][2][row] + red[1][3][row];
            float mean = tot * (1.f / 256.f);
            float var  = tq * (1.f / 256.f) - mean * mean;
            float rs = rsqrtf(var + 1e-5f);
            long row_g = block0 + row;
            float* po = out + row_g * 256 + wbase;
            #pragma unroll
            for (int nf = 0; nf < 4; ++nf)
                po[nf * 16 + l15] = rs * (acc[mf][nf][i] - mean * K1v[nf]) + K2v[nf];
        }
}

// ---------------- fallback: R11 fused kernel (427 us), used if ws too small ----
__global__ __launch_bounds__(512, 4)
void fused_fallback(const float* __restrict__ var_grid, const int* __restrict__ idxs,
                    const unsigned short* __restrict__ bp1, const unsigned short* __restrict__ bp2,
                    const float* __restrict__ latT, const float* __restrict__ lonT,
                    const float* __restrict__ b1p, const float* __restrict__ K1,
                    const float* __restrict__ K2,
                    float* __restrict__ out)
{
    __shared__ __align__(16) unsigned short h_lds[64 * 256];
    __shared__ float red[2][4][64];
    unsigned short (*x_lds)[104] = (unsigned short (*)[104])h_lds;

    const int q_ = 1470, r_ = 4;   // nwg=11764
    const int xcd = blockIdx.x & 7;
    const int ii  = blockIdx.x >> 3;
    const int swz = (xcd < r_ ? xcd * (q_ + 1) : r_ * (q_ + 1) + (xcd - r_) * q_) + ii;

    const int tid  = threadIdx.x;
    const int lane = tid & 63;
    const int wave = tid >> 6;
    const int wr   = wave >> 2;
    const int wc   = wave & 3;
    const int l15  = lane & 15;
    const int lg   = lane >> 4;
    const int wbase = wc * 64;
    const int rbase = wr * 32;
    const long block0 = (long)swz * 64;

    {
        const int row = tid >> 3, p = tid & 7;
        const int idx = idxs[block0 + row];
        const int hh = idx / GW;
        const int ww = idx - hh * GW;
        const float* src = var_grid + (long)idx * C_IN;
        float2 g[5], tl, tl2;
        #pragma unroll
        for (int t = 0; t < 5; ++t) {
            const int q = p + 8 * t;
            if (q < 39) g[t] = *(const float2*)(src + 2 * q);
        }
        tl.x  = latT[2 * hh]; tl.y  = latT[2 * hh + 1];
        tl2.x = lonT[2 * ww]; tl2.y = lonT[2 * ww + 1];
        unsigned int* xrow = (unsigned int*)&x_lds[row][0];
        #pragma unroll
        for (int t = 0; t < 6; ++t) {
            const int q = p + 8 * t;
            float v0, v1;
            if (q < 39)      { v0 = g[t].x; v1 = g[t].y; }
            else if (q == 39){ v0 = tl.x;  v1 = tl.y; }
            else if (q == 40){ v0 = tl2.x; v1 = tl2.y; }
            else             { v0 = 0.f; v1 = 0.f; }
            xrow[q] = ((unsigned int)f2bf(v1) << 16) | (unsigned int)f2bf(v0);
        }
    }

    float b1v[4];
    #pragma unroll
    for (int nf = 0; nf < 4; ++nf) b1v[nf] = b1p[wbase + nf * 16 + l15];
    __syncthreads();

    f32x4 acc[2][4];
    #pragma unroll
    for (int mf = 0; mf < 2; ++mf)
        #pragma unroll
        for (int nf = 0; nf < 4; ++nf) acc[mf][nf] = (f32x4){0.f, 0.f, 0.f, 0.f};

    #pragma unroll
    for (int s = 0; s < 3; ++s) {
        bf16x8 af[2], bw[4];
        #pragma unroll
        for (int nf = 0; nf < 4; ++nf)
            bw[nf] = *(const bf16x8*)(bp1 + ((size_t)((s * 4 + lg) * 256) + wbase + nf * 16 + l15) * 8);
        #pragma unroll
        for (int mf = 0; mf < 2; ++mf)
            af[mf] = *(const bf16x8*)&x_lds[rbase + mf * 16 + l15][s * 32 + lg * 8];
        #pragma unroll
        for (int mf = 0; mf < 2; ++mf)
            #pragma unroll
            for (int nf = 0; nf < 4; ++nf)
                acc[mf][nf] = __builtin_amdgcn_mfma_f32_16x16x32_bf16(af[mf], bw[nf], acc[mf][nf], 0, 0, 0);
    }

    __syncthreads();

    float sm[2][4], sq[2][4];
    #pragma unroll
    for (int mf = 0; mf < 2; ++mf)
        #pragma unroll
        for (int i = 0; i < 4; ++i) { sm[mf][i] = 0.f; sq[mf][i] = 0.f; }

    #pragma unroll
    for (int mf = 0; mf < 2; ++mf)
        #pragma unroll
        for (int nf = 0; nf < 4; ++nf)
            #pragma unroll
            for (int i = 0; i < 4; ++i) {
                float v = fmaxf(acc[mf][nf][i] + b1v[nf], 0.f);
                sm[mf][i] += v;
                sq[mf][i] += v * v;
                int row = rbase + mf * 16 + lg * 4 + i;
                int col = wbase + nf * 16 + l15;
                unsigned off = (unsigned)(row * 512 + col * 2);
                off ^= (unsigned)((row & 7) << 4);
                *(unsigned short*)((char*)h_lds + off) = f2bf(v);
            }

    #pragma unroll
    for (int m = 1; m < 16; m <<= 1)
        #pragma unroll
        for (int mf = 0; mf < 2; ++mf)
            #pragma unroll
            for (int i = 0; i < 4; ++i) {
                sm[mf][i] += __shfl_xor(sm[mf][i], m, 64);
                sq[mf][i] += __shfl_xor(sq[mf][i], m, 64);
            }

    if (l15 == 0) {
        #pragma unroll
        for (int mf = 0; mf < 2; ++mf)
            #pragma unroll
            for (int i = 0; i < 4; ++i) {
                int row = rbase + mf * 16 + lg * 4 + i;
                red[0][wc][row] = sm[mf][i];
                red[1][wc][row] = sq[mf][i];
            }
    }
    __syncthreads();

    #pragma unroll
    for (int mf = 0; mf < 2; ++mf)
        #pragma unroll
        for (int nf = 0; nf < 4; ++nf) acc[mf][nf] = (f32x4){0.f, 0.f, 0.f, 0.f};

    #pragma unroll
    for (int s = 0; s < 8; ++s) {
        bf16x8 af[2], bw[4];
        #pragma unroll
        for (int nf = 0; nf < 4; ++nf)
            bw[nf] = *(const bf16x8*)(bp2 + ((size_t)((s * 4 + lg) * 256) + wbase + nf * 16 + l15) * 8);
        #pragma unroll
        for (int mf = 0; mf < 2; ++mf) {
            int row = rbase + mf * 16 + l15;
            unsigned off = (unsigned)(row * 512 + (s * 32 + lg * 8) * 2);
            off ^= (unsigned)((row & 7) << 4);
            af[mf] = *(const bf16x8*)((char*)h_lds + off);
        }
        #pragma unroll
        for (int mf = 0; mf < 2; ++mf)
            #pragma unroll
            for (int nf = 0; nf < 4; ++nf)
                acc[mf][nf] = __builtin_amdgcn_mfma_f32_16x16x32_bf16(af[mf], bw[nf], acc[mf][nf], 0, 0, 0);
    }

    float K1v[4], K2v[4];
    #pragma unroll
    for (int nf = 0; nf < 4; ++nf) {
        int col = wbase + nf * 16 + l15;
        K1v[nf] = K1[col]; K2v[nf] = K2[col];
    }
    #pragma unroll
    for (int mf = 0; mf < 2; ++mf)
        #pragma unroll
        for (int i = 0; i < 4; ++i) {
            int row = rbase + mf * 16 + lg * 4 + i;
            float tot = red[0][0][row] + red[0][1][row] + red[0][2][row] + red[0][3][row];
            float tq  = red[1][0][row] + red[1][1][row] + red[1][2][row] + red[1][3][row];
            float mean = tot * (1.f / 256.f);
            float var  = tq * (1.f / 256.f) - mean * mean;
            float rs = rsqrtf(var + 1e-5f);
            long row_g = block0 + row;
            float* po = out + row_g * 256 + wbase;
            #pragma unroll
            for (int nf = 0; nf < 4; ++nf)
                po[nf * 16 + l15] = rs * (acc[mf][nf][i] - mean * K1v[nf]) + K2v[nf];
        }
}

extern "C" void kernel_launch(void* const* d_in, const int* in_sizes, int n_in,
                              void* d_out, int out_size, void* d_ws, size_t ws_size,
                              hipStream_t stream) {
    const float* var_grid = (const float*)d_in[0];
    const int*   idxs     = (const int*)d_in[1];
    const float* means    = (const float*)d_in[2];
    const float* stds     = (const float*)d_in[3];
    const float* W1       = (const float*)d_in[4];
    const float* b1       = (const float*)d_in[5];
    const float* lnS      = (const float*)d_in[6];
    const float* lnO      = (const float*)d_in[7];
    const float* W2       = (const float*)d_in[8];
    const float* b2       = (const float*)d_in[9];
    float* out = (float*)d_out;

    const size_t XBUF_BYTES = (size_t)M_TOTAL * 96 * 2;   // 144,556,032
    char* ws = (char*)d_ws;

    if (ws_size >= XBUF_BYTES + 262144) {
        // ---- split path: gather kernel + streaming MLP kernel ----
        unsigned short* xbuf = (unsigned short*)ws;
        char* aux = ws + XBUF_BYTES;
        unsigned short* bp1 = (unsigned short*)aux;              // 49152 B
        unsigned short* bp2 = (unsigned short*)(aux + 49152);    // 131072 B
        float* latT = (float*)(aux + 180224);                    // 5768 B
        float* lonT = (float*)(aux + 186000);                    // 11520 B
        float* b1p  = (float*)(aux + 197520);                    // 1024 B
        float* K1   = (float*)(aux + 198544);                    // 1024 B
        float* K2   = (float*)(aux + 199568);                    // 1024 B

        prep_kernel<<<362, 256, 0, stream>>>(W1, W2, means, stds, b1, lnS, lnO, b2,
                                             bp1, bp2, latT, lonT, b1p, K1, K2);
        gather_kernel<<<2048, 256, 0, stream>>>(var_grid, idxs, latT, lonT, xbuf);
        mlp_kernel<<<M_TOTAL / 64, 512, 0, stream>>>(xbuf, bp1, bp2, b1p, K1, K2, out);
    } else {
        // ---- fallback: R11 single fused kernel ----
        unsigned short* bp1 = (unsigned short*)ws;
        unsigned short* bp2 = (unsigned short*)(ws + 49152);
        float* latT = (float*)(ws + 180224);
        float* lonT = (float*)(ws + 186000);
        float* b1p  = (float*)(ws + 197520);
        float* K1   = (float*)(ws + 198544);
        float* K2   = (float*)(ws + 199568);

        prep_kernel<<<362, 256, 0, stream>>>(W1, W2, means, stds, b1, lnS, lnO, b2,
                                             bp1, bp2, latT, lonT, b1p, K1, K2);
        fused_fallback<<<M_TOTAL / 64, 512, 0, stream>>>(var_grid, idxs, bp1, bp2,
                                                         latT, lonT, b1p, K1, K2, out);
    }
}

// Round 17
// 428.720 us; speedup vs baseline: 4.2691x; 1.2256x over previous
//
#include <hip/hip_runtime.h>
#include <hip/hip_bf16.h>
#include <math.h>

#define GH 721
#define GW 1440
#define C_IN 78
#define NNODES 5882
#define KNEIGH 128
#define M_TOTAL (NNODES * KNEIGH)   // 752896
#define TM 64
#define NBLOCKS (M_TOTAL / TM)      // 11764

typedef __attribute__((ext_vector_type(8))) short bf16x8;
typedef __attribute__((ext_vector_type(4))) float f32x4;

__device__ __forceinline__ unsigned short f2bf(float x) {
    __hip_bfloat16 b = __float2bfloat16(x);
    union { __hip_bfloat16 h; unsigned short u; } cv; cv.h = b; return cv.u;
}

// ---------------- prep kernel (unchanged from R11) ----------------
__global__ void prep_kernel(const float* __restrict__ W1, const float* __restrict__ W2,
                            const float* __restrict__ means, const float* __restrict__ stds,
                            const float* __restrict__ b1, const float* __restrict__ lnS,
                            const float* __restrict__ lnO, const float* __restrict__ b2,
                            unsigned short* __restrict__ bp1, unsigned short* __restrict__ bp2,
                            float* __restrict__ latT, float* __restrict__ lonT,
                            float* __restrict__ b1p, float* __restrict__ K1,
                            float* __restrict__ K2)
{
    const int NB1 = 3 * 4 * 256 * 8;   // 24576
    const int NB2 = 8 * 4 * 256 * 8;   // 65536
    const int NTOT = NB1 + NB2 + GH + GW + 256;
    for (int e = blockIdx.x * blockDim.x + threadIdx.x; e < NTOT;
         e += gridDim.x * blockDim.x) {
        if (e < NB1) {
            int j = e & 7, c = (e >> 3) & 255, o = (e >> 11) & 3, s = e >> 13;
            int k = s * 32 + o * 8 + j;
            float v = 0.f;
            if (k < 82) v = W1[k * 256 + c] / (stds[k] + 1e-7f);
            bp1[e] = f2bf(v);
        } else if (e < NB1 + NB2) {
            int t = e - NB1;
            int j = t & 7, c = (t >> 3) & 255, o = (t >> 11) & 3, s = t >> 13;
            int k = s * 32 + o * 8 + j;
            bp2[t] = f2bf(W2[k * 256 + c] * lnS[k]);
        } else if (e < NB1 + NB2 + GH) {
            int h = e - NB1 - NB2;
            float r = (-90.f + 0.25f * (float)h) * 0.017453292519943295f;
            latT[2 * h]     = sinf(r);
            latT[2 * h + 1] = cosf(r);
        } else if (e < NB1 + NB2 + GH + GW) {
            int w = e - NB1 - NB2 - GH;
            float r = ((float)w * (360.f / 1439.f)) * 0.017453292519943295f;
            lonT[2 * w]     = sinf(r);
            lonT[2 * w + 1] = cosf(r);
        } else {
            int c = e - NB1 - NB2 - GH - GW;   // output/hidden column 0..255
            float acc = b1[c];
            #pragma unroll 1
            for (int k = 0; k < 86; ++k) {
                float inv = 1.f / (stds[k] + 1e-7f);
                float w = W1[k * 256 + c] * inv;
                acc -= means[k] * w;
                if (k == 82) acc += 0.5f * w;   // day-of-year channel, raw value 0.5
            }
            b1p[c] = acc;
            float k1 = 0.f, k2 = 0.f;
            #pragma unroll 1
            for (int k = 0; k < 256; ++k) {
                float w = W2[k * 256 + c];
                k1 += lnS[k] * w;
                k2 += lnO[k] * w;
            }
            K1[c] = k1;
            K2[c] = k2 + b2[c];
        }
    }
}

// ---------------- fused kernel: R11 structure, x/h un-aliased -> 2 barriers ----------------
// Wave tile 32x64, acc[2][4]=32 regs; ~96 unified regs < 128 cap -> 16 waves/CU,
// no spill. Separate x_lds removes the alias-protection barrier between GEMM1 and
// the ReLU/h pass (each wave writes only its own h columns).
__global__ __launch_bounds__(512, 4)
void fused_kernel(const float* __restrict__ var_grid, const int* __restrict__ idxs,
                  const unsigned short* __restrict__ bp1, const unsigned short* __restrict__ bp2,
                  const float* __restrict__ latT, const float* __restrict__ lonT,
                  const float* __restrict__ b1p, const float* __restrict__ K1,
                  const float* __restrict__ K2,
                  float* __restrict__ out)
{
    __shared__ __align__(16) unsigned short x_lds[TM][104];   // 13312 B
    __shared__ __align__(16) unsigned short h_lds[TM * 256];  // 32768 B, XOR-swizzled
    __shared__ float red[2][4][TM];                           // 2048 B

    // Bijective XCD-aware swizzle (nwg=11764, q=1470, r=4)
    const int q_ = 1470, r_ = 4;
    const int xcd = blockIdx.x & 7;
    const int ii  = blockIdx.x >> 3;
    const int swz = (xcd < r_ ? xcd * (q_ + 1) : r_ * (q_ + 1) + (xcd - r_) * q_) + ii;

    const int tid  = threadIdx.x;
    const int lane = tid & 63;
    const int wave = tid >> 6;       // 0..7
    const int wr   = wave >> 2;      // 0..1  row half (32 rows)
    const int wc   = wave & 3;       // 0..3  col quarter (64 cols)
    const int l15  = lane & 15;
    const int lg   = lane >> 4;      // 0..3
    const int wbase = wc * 64;
    const int rbase = wr * 32;
    const long block0 = (long)swz * TM;

    // ---- gather: 8 lanes/row, batch loads -> regs, pack -> LDS ----
    {
        const int row = tid >> 3, p = tid & 7;     // rows 0..63
        const int idx = idxs[block0 + row];
        const int hh = idx / GW;
        const int ww = idx - hh * GW;
        const float* src = var_grid + (long)idx * C_IN;
        float2 g[5], tl, tl2;
        #pragma unroll
        for (int t = 0; t < 5; ++t) {
            const int q = p + 8 * t;
            if (q < 39) g[t] = *(const float2*)(src + 2 * q);
        }
        tl.x  = latT[2 * hh]; tl.y  = latT[2 * hh + 1];
        tl2.x = lonT[2 * ww]; tl2.y = lonT[2 * ww + 1];
        unsigned int* xrow = (unsigned int*)&x_lds[row][0];
        #pragma unroll
        for (int t = 0; t < 6; ++t) {
            const int q = p + 8 * t;
            float v0, v1;
            if (q < 39)      { v0 = g[t].x; v1 = g[t].y; }
            else if (q == 39){ v0 = tl.x;  v1 = tl.y; }
            else if (q == 40){ v0 = tl2.x; v1 = tl2.y; }
            else             { v0 = 0.f; v1 = 0.f; }   // ch 82..95 folded / pad
            xrow[q] = ((unsigned int)f2bf(v1) << 16) | (unsigned int)f2bf(v0);
        }
    }

    float b1v[4];
    #pragma unroll
    for (int nf = 0; nf < 4; ++nf) b1v[nf] = b1p[wbase + nf * 16 + l15];
    __syncthreads();   // barrier 1: x visible

    // ---- GEMM1: x[64x96] @ W1'[96x256] ----
    f32x4 acc[2][4];
    #pragma unroll
    for (int mf = 0; mf < 2; ++mf)
        #pragma unroll
        for (int nf = 0; nf < 4; ++nf) acc[mf][nf] = (f32x4){0.f, 0.f, 0.f, 0.f};

    #pragma unroll
    for (int s = 0; s < 3; ++s) {
        bf16x8 af[2], bw[4];
        #pragma unroll
        for (int nf = 0; nf < 4; ++nf)
            bw[nf] = *(const bf16x8*)(bp1 + ((size_t)((s * 4 + lg) * 256) + wbase + nf * 16 + l15) * 8);
        #pragma unroll
        for (int mf = 0; mf < 2; ++mf)
            af[mf] = *(const bf16x8*)&x_lds[rbase + mf * 16 + l15][s * 32 + lg * 8];
        #pragma unroll
        for (int mf = 0; mf < 2; ++mf)
            #pragma unroll
            for (int nf = 0; nf < 4; ++nf)
                acc[mf][nf] = __builtin_amdgcn_mfma_f32_16x16x32_bf16(af[mf], bw[nf], acc[mf][nf], 0, 0, 0);
    }

    // ---- bias + ReLU -> h (own columns; x untouched -> no barrier needed) ----
    float sm[2][4], sq[2][4];
    #pragma unroll
    for (int mf = 0; mf < 2; ++mf)
        #pragma unroll
        for (int i = 0; i < 4; ++i) { sm[mf][i] = 0.f; sq[mf][i] = 0.f; }

    #pragma unroll
    for (int mf = 0; mf < 2; ++mf)
        #pragma unroll
        for (int nf = 0; nf < 4; ++nf)
            #pragma unroll
            for (int i = 0; i < 4; ++i) {
                float v = fmaxf(acc[mf][nf][i] + b1v[nf], 0.f);
                sm[mf][i] += v;
                sq[mf][i] += v * v;
                int row = rbase + mf * 16 + lg * 4 + i;
                int col = wbase + nf * 16 + l15;
                unsigned off = (unsigned)(row * 512 + col * 2);
                off ^= (unsigned)((row & 7) << 4);
                *(unsigned short*)((char*)h_lds + off) = f2bf(v);
            }

    #pragma unroll
    for (int m = 1; m < 16; m <<= 1)
        #pragma unroll
        for (int mf = 0; mf < 2; ++mf)
            #pragma unroll
            for (int i = 0; i < 4; ++i) {
                sm[mf][i] += __shfl_xor(sm[mf][i], m, 64);
                sq[mf][i] += __shfl_xor(sq[mf][i], m, 64);
            }

    if (l15 == 0) {
        #pragma unroll
        for (int mf = 0; mf < 2; ++mf)
            #pragma unroll
            for (int i = 0; i < 4; ++i) {
                int row = rbase + mf * 16 + lg * 4 + i;
                red[0][wc][row] = sm[mf][i];
                red[1][wc][row] = sq[mf][i];
            }
    }
    __syncthreads();   // barrier 2: h + red visible

    // ---- GEMM2: h[64x256] @ W2'[256x256]  (P = relu_h @ lnS*W2) ----
    #pragma unroll
    for (int mf = 0; mf < 2; ++mf)
        #pragma unroll
        for (int nf = 0; nf < 4; ++nf) acc[mf][nf] = (f32x4){0.f, 0.f, 0.f, 0.f};

    #pragma unroll
    for (int s = 0; s < 8; ++s) {
        bf16x8 af[2], bw[4];
        #pragma unroll
        for (int nf = 0; nf < 4; ++nf)
            bw[nf] = *(const bf16x8*)(bp2 + ((size_t)((s * 4 + lg) * 256) + wbase + nf * 16 + l15) * 8);
        #pragma unroll
        for (int mf = 0; mf < 2; ++mf) {
            int row = rbase + mf * 16 + l15;
            unsigned off = (unsigned)(row * 512 + (s * 32 + lg * 8) * 2);
            off ^= (unsigned)((row & 7) << 4);
            af[mf] = *(const bf16x8*)((char*)h_lds + off);
        }
        #pragma unroll
        for (int mf = 0; mf < 2; ++mf)
            #pragma unroll
            for (int nf = 0; nf < 4; ++nf)
                acc[mf][nf] = __builtin_amdgcn_mfma_f32_16x16x32_bf16(af[mf], bw[nf], acc[mf][nf], 0, 0, 0);
    }

    // ---- epilogue: LN applied algebraically; direct plain stores ----
    float K1v[4], K2v[4];
    #pragma unroll
    for (int nf = 0; nf < 4; ++nf) {
        int col = wbase + nf * 16 + l15;
        K1v[nf] = K1[col]; K2v[nf] = K2[col];
    }
    #pragma unroll
    for (int mf = 0; mf < 2; ++mf)
        #pragma unroll
        for (int i = 0; i < 4; ++i) {
            int row = rbase + mf * 16 + lg * 4 + i;
            float tot = red[0][0][row] + red[0][1][row] + red[0][2][row] + red[0][3][row];
            float tq  = red[1][0][row] + red[1][1][row] + red[1][2][row] + red[1][3][row];
            float mean = tot * (1.f / 256.f);
            float var  = tq * (1.f / 256.f) - mean * mean;
            float rs = rsqrtf(var + 1e-5f);
            long row_g = block0 + row;
            float* po = out + row_g * 256 + wbase;
            #pragma unroll
            for (int nf = 0; nf < 4; ++nf)
                po[nf * 16 + l15] = rs * (acc[mf][nf][i] - mean * K1v[nf]) + K2v[nf];
        }
}

extern "C" void kernel_launch(void* const* d_in, const int* in_sizes, int n_in,
                              void* d_out, int out_size, void* d_ws, size_t ws_size,
                              hipStream_t stream) {
    const float* var_grid = (const float*)d_in[0];
    const int*   idxs     = (const int*)d_in[1];
    const float* means    = (const float*)d_in[2];
    const float* stds     = (const float*)d_in[3];
    const float* W1       = (const float*)d_in[4];
    const float* b1       = (const float*)d_in[5];
    const float* lnS      = (const float*)d_in[6];
    const float* lnO      = (const float*)d_in[7];
    const float* W2       = (const float*)d_in[8];
    const float* b2       = (const float*)d_in[9];
    float* out = (float*)d_out;

    char* ws = (char*)d_ws;
    unsigned short* bp1 = (unsigned short*)ws;               // 49152 B
    unsigned short* bp2 = (unsigned short*)(ws + 49152);     // 131072 B -> 180224
    float* latT = (float*)(ws + 180224);                     // 5768 B
    float* lonT = (float*)(ws + 186000);                     // 11520 B
    float* b1p  = (float*)(ws + 197520);                     // 1024 B
    float* K1   = (float*)(ws + 198544);                     // 1024 B
    float* K2   = (float*)(ws + 199568);                     // 1024 B (end 200592)

    prep_kernel<<<362, 256, 0, stream>>>(W1, W2, means, stds, b1, lnS, lnO, b2,
                                         bp1, bp2, latT, lonT, b1p, K1, K2);
    fused_kernel<<<NBLOCKS, 512, 0, stream>>>(var_grid, idxs, bp1, bp2, latT, lonT,
                                              b1p, K1, K2, out);
}

// Round 18
// 426.780 us; speedup vs baseline: 4.2885x; 1.0045x over previous
//
#include <hip/hip_runtime.h>
#include <hip/hip_bf16.h>
#include <math.h>

#define GH 721
#define GW 1440
#define C_IN 78
#define NNODES 5882
#define KNEIGH 128
#define M_TOTAL (NNODES * KNEIGH)   // 752896
#define TM 64
#define NBLOCKS (M_TOTAL / TM)      // 11764

typedef __attribute__((ext_vector_type(8))) short bf16x8;
typedef __attribute__((ext_vector_type(4))) float f32x4;

__device__ __forceinline__ unsigned short f2bf(float x) {
    __hip_bfloat16 b = __float2bfloat16(x);
    union { __hip_bfloat16 h; unsigned short u; } cv; cv.h = b; return cv.u;
}

// ---------------- prep kernel (unchanged from R11) ----------------
__global__ void prep_kernel(const float* __restrict__ W1, const float* __restrict__ W2,
                            const float* __restrict__ means, const float* __restrict__ stds,
                            const float* __restrict__ b1, const float* __restrict__ lnS,
                            const float* __restrict__ lnO, const float* __restrict__ b2,
                            unsigned short* __restrict__ bp1, unsigned short* __restrict__ bp2,
                            float* __restrict__ latT, float* __restrict__ lonT,
                            float* __restrict__ b1p, float* __restrict__ K1,
                            float* __restrict__ K2)
{
    const int NB1 = 3 * 4 * 256 * 8;   // 24576
    const int NB2 = 8 * 4 * 256 * 8;   // 65536
    const int NTOT = NB1 + NB2 + GH + GW + 256;
    for (int e = blockIdx.x * blockDim.x + threadIdx.x; e < NTOT;
         e += gridDim.x * blockDim.x) {
        if (e < NB1) {
            int j = e & 7, c = (e >> 3) & 255, o = (e >> 11) & 3, s = e >> 13;
            int k = s * 32 + o * 8 + j;
            float v = 0.f;
            if (k < 82) v = W1[k * 256 + c] / (stds[k] + 1e-7f);
            bp1[e] = f2bf(v);
        } else if (e < NB1 + NB2) {
            int t = e - NB1;
            int j = t & 7, c = (t >> 3) & 255, o = (t >> 11) & 3, s = t >> 13;
            int k = s * 32 + o * 8 + j;
            bp2[t] = f2bf(W2[k * 256 + c] * lnS[k]);
        } else if (e < NB1 + NB2 + GH) {
            int h = e - NB1 - NB2;
            float r = (-90.f + 0.25f * (float)h) * 0.017453292519943295f;
            latT[2 * h]     = sinf(r);
            latT[2 * h + 1] = cosf(r);
        } else if (e < NB1 + NB2 + GH + GW) {
            int w = e - NB1 - NB2 - GH;
            float r = ((float)w * (360.f / 1439.f)) * 0.017453292519943295f;
            lonT[2 * w]     = sinf(r);
            lonT[2 * w + 1] = cosf(r);
        } else {
            int c = e - NB1 - NB2 - GH - GW;   // output/hidden column 0..255
            float acc = b1[c];
            #pragma unroll 1
            for (int k = 0; k < 86; ++k) {
                float inv = 1.f / (stds[k] + 1e-7f);
                float w = W1[k * 256 + c] * inv;
                acc -= means[k] * w;
                if (k == 82) acc += 0.5f * w;   // day-of-year channel, raw value 0.5
            }
            b1p[c] = acc;
            float k1 = 0.f, k2 = 0.f;
            #pragma unroll 1
            for (int k = 0; k < 256; ++k) {
                float w = W2[k * 256 + c];
                k1 += lnS[k] * w;
                k2 += lnO[k] * w;
            }
            K1[c] = k1;
            K2[c] = k2 + b2[c];
        }
    }
}

// ---------------- fused kernel: R17 + one-step bw prefetch ----------------
// The per-step latency chain (4 L2 bw loads ~200cy feeding 8 MFMAs ~40cy) is
// the measured stall (MfmaUtil 11%, VALUBusy 25%, all pipes idle). Explicit
// bwn double-buffer (+16 regs) hides it; budget ~112 < 128 cap -> 16 waves/CU,
// no spill (prefetch was only ever tested in spill-regime kernels R4/R5).
__global__ __launch_bounds__(512, 4)
void fused_kernel(const float* __restrict__ var_grid, const int* __restrict__ idxs,
                  const unsigned short* __restrict__ bp1, const unsigned short* __restrict__ bp2,
                  const float* __restrict__ latT, const float* __restrict__ lonT,
                  const float* __restrict__ b1p, const float* __restrict__ K1,
                  const float* __restrict__ K2,
                  float* __restrict__ out)
{
    __shared__ __align__(16) unsigned short x_lds[TM][104];   // 13312 B
    __shared__ __align__(16) unsigned short h_lds[TM * 256];  // 32768 B, XOR-swizzled
    __shared__ float red[2][4][TM];                           // 2048 B

    // Bijective XCD-aware swizzle (nwg=11764, q=1470, r=4)
    const int q_ = 1470, r_ = 4;
    const int xcd = blockIdx.x & 7;
    const int ii  = blockIdx.x >> 3;
    const int swz = (xcd < r_ ? xcd * (q_ + 1) : r_ * (q_ + 1) + (xcd - r_) * q_) + ii;

    const int tid  = threadIdx.x;
    const int lane = tid & 63;
    const int wave = tid >> 6;       // 0..7
    const int wr   = wave >> 2;      // 0..1  row half (32 rows)
    const int wc   = wave & 3;       // 0..3  col quarter (64 cols)
    const int l15  = lane & 15;
    const int lg   = lane >> 4;      // 0..3
    const int wbase = wc * 64;
    const int rbase = wr * 32;
    const long block0 = (long)swz * TM;

    // per-thread weight-fragment base pointers (compile-time step offsets fold in)
    const unsigned short* bp1t = bp1 + ((size_t)(lg * 256) + wbase + l15) * 8;
    const unsigned short* bp2t = bp2 + ((size_t)(lg * 256) + wbase + l15) * 8;

    // ---- gather: 8 lanes/row, batch loads -> regs, pack -> LDS ----
    {
        const int row = tid >> 3, p = tid & 7;     // rows 0..63
        const int idx = idxs[block0 + row];
        const int hh = idx / GW;
        const int ww = idx - hh * GW;
        const float* src = var_grid + (long)idx * C_IN;
        float2 g[5], tl, tl2;
        #pragma unroll
        for (int t = 0; t < 5; ++t) {
            const int q = p + 8 * t;
            if (q < 39) g[t] = *(const float2*)(src + 2 * q);
        }
        tl.x  = latT[2 * hh]; tl.y  = latT[2 * hh + 1];
        tl2.x = lonT[2 * ww]; tl2.y = lonT[2 * ww + 1];
        unsigned int* xrow = (unsigned int*)&x_lds[row][0];
        #pragma unroll
        for (int t = 0; t < 6; ++t) {
            const int q = p + 8 * t;
            float v0, v1;
            if (q < 39)      { v0 = g[t].x; v1 = g[t].y; }
            else if (q == 39){ v0 = tl.x;  v1 = tl.y; }
            else if (q == 40){ v0 = tl2.x; v1 = tl2.y; }
            else             { v0 = 0.f; v1 = 0.f; }   // ch 82..95 folded / pad
            xrow[q] = ((unsigned int)f2bf(v1) << 16) | (unsigned int)f2bf(v0);
        }
    }

    float b1v[4];
    #pragma unroll
    for (int nf = 0; nf < 4; ++nf) b1v[nf] = b1p[wbase + nf * 16 + l15];
    __syncthreads();   // barrier 1: x visible

    // ---- GEMM1: x[64x96] @ W1'[96x256], bw prefetched one step ahead ----
    f32x4 acc[2][4];
    #pragma unroll
    for (int mf = 0; mf < 2; ++mf)
        #pragma unroll
        for (int nf = 0; nf < 4; ++nf) acc[mf][nf] = (f32x4){0.f, 0.f, 0.f, 0.f};

    bf16x8 bw[4], bwn[4];
    #pragma unroll
    for (int nf = 0; nf < 4; ++nf)
        bw[nf] = *(const bf16x8*)(bp1t + ((size_t)nf * 16) * 8);

    #pragma unroll
    for (int s = 0; s < 3; ++s) {
        if (s < 2)
            #pragma unroll
            for (int nf = 0; nf < 4; ++nf)
                bwn[nf] = *(const bf16x8*)(bp1t + ((size_t)(s + 1) * 4 * 256 + nf * 16) * 8);
        bf16x8 af[2];
        #pragma unroll
        for (int mf = 0; mf < 2; ++mf)
            af[mf] = *(const bf16x8*)&x_lds[rbase + mf * 16 + l15][s * 32 + lg * 8];
        #pragma unroll
        for (int mf = 0; mf < 2; ++mf)
            #pragma unroll
            for (int nf = 0; nf < 4; ++nf)
                acc[mf][nf] = __builtin_amdgcn_mfma_f32_16x16x32_bf16(af[mf], bw[nf], acc[mf][nf], 0, 0, 0);
        #pragma unroll
        for (int nf = 0; nf < 4; ++nf) bw[nf] = bwn[nf];
    }

    // ---- bias + ReLU -> h (own columns; x untouched -> no barrier needed) ----
    float sm[2][4], sq[2][4];
    #pragma unroll
    for (int mf = 0; mf < 2; ++mf)
        #pragma unroll
        for (int i = 0; i < 4; ++i) { sm[mf][i] = 0.f; sq[mf][i] = 0.f; }

    #pragma unroll
    for (int mf = 0; mf < 2; ++mf)
        #pragma unroll
        for (int nf = 0; nf < 4; ++nf)
            #pragma unroll
            for (int i = 0; i < 4; ++i) {
                float v = fmaxf(acc[mf][nf][i] + b1v[nf], 0.f);
                sm[mf][i] += v;
                sq[mf][i] += v * v;
                int row = rbase + mf * 16 + lg * 4 + i;
                int col = wbase + nf * 16 + l15;
                unsigned off = (unsigned)(row * 512 + col * 2);
                off ^= (unsigned)((row & 7) << 4);
                *(unsigned short*)((char*)h_lds + off) = f2bf(v);
            }

    #pragma unroll
    for (int m = 1; m < 16; m <<= 1)
        #pragma unroll
        for (int mf = 0; mf < 2; ++mf)
            #pragma unroll
            for (int i = 0; i < 4; ++i) {
                sm[mf][i] += __shfl_xor(sm[mf][i], m, 64);
                sq[mf][i] += __shfl_xor(sq[mf][i], m, 64);
            }

    if (l15 == 0) {
        #pragma unroll
        for (int mf = 0; mf < 2; ++mf)
            #pragma unroll
            for (int i = 0; i < 4; ++i) {
                int row = rbase + mf * 16 + lg * 4 + i;
                red[0][wc][row] = sm[mf][i];
                red[1][wc][row] = sq[mf][i];
            }
    }

    // prefetch GEMM2 step-0 weights BEFORE the barrier (hides under barrier wait)
    #pragma unroll
    for (int nf = 0; nf < 4; ++nf)
        bw[nf] = *(const bf16x8*)(bp2t + ((size_t)nf * 16) * 8);

    __syncthreads();   // barrier 2: h + red visible

    // ---- GEMM2: h[64x256] @ W2'[256x256], bw prefetched one step ahead ----
    #pragma unroll
    for (int mf = 0; mf < 2; ++mf)
        #pragma unroll
        for (int nf = 0; nf < 4; ++nf) acc[mf][nf] = (f32x4){0.f, 0.f, 0.f, 0.f};

    #pragma unroll
    for (int s = 0; s < 8; ++s) {
        if (s < 7)
            #pragma unroll
            for (int nf = 0; nf < 4; ++nf)
                bwn[nf] = *(const bf16x8*)(bp2t + ((size_t)(s + 1) * 4 * 256 + nf * 16) * 8);
        bf16x8 af[2];
        #pragma unroll
        for (int mf = 0; mf < 2; ++mf) {
            int row = rbase + mf * 16 + l15;
            unsigned off = (unsigned)(row * 512 + (s * 32 + lg * 8) * 2);
            off ^= (unsigned)((row & 7) << 4);
            af[mf] = *(const bf16x8*)((char*)h_lds + off);
        }
        #pragma unroll
        for (int mf = 0; mf < 2; ++mf)
            #pragma unroll
            for (int nf = 0; nf < 4; ++nf)
                acc[mf][nf] = __builtin_amdgcn_mfma_f32_16x16x32_bf16(af[mf], bw[nf], acc[mf][nf], 0, 0, 0);
        #pragma unroll
        for (int nf = 0; nf < 4; ++nf) bw[nf] = bwn[nf];
    }

    // ---- epilogue: LN applied algebraically; direct plain stores ----
    float K1v[4], K2v[4];
    #pragma unroll
    for (int nf = 0; nf < 4; ++nf) {
        int col = wbase + nf * 16 + l15;
        K1v[nf] = K1[col]; K2v[nf] = K2[col];
    }
    #pragma unroll
    for (int mf = 0; mf < 2; ++mf)
        #pragma unroll
        for (int i = 0; i < 4; ++i) {
            int row = rbase + mf * 16 + lg * 4 + i;
            float tot = red[0][0][row] + red[0][1][row] + red[0][2][row] + red[0][3][row];
            float tq  = red[1][0][row] + red[1][1][row] + red[1][2][row] + red[1][3][row];
            float mean = tot * (1.f / 256.f);
            float var  = tq * (1.f / 256.f) - mean * mean;
            float rs = rsqrtf(var + 1e-5f);
            long row_g = block0 + row;
            float* po = out + row_g * 256 + wbase;
            #pragma unroll
            for (int nf = 0; nf < 4; ++nf)
                po[nf * 16 + l15] = rs * (acc[mf][nf][i] - mean * K1v[nf]) + K2v[nf];
        }
}

extern "C" void kernel_launch(void* const* d_in, const int* in_sizes, int n_in,
                              void* d_out, int out_size, void* d_ws, size_t ws_size,
                              hipStream_t stream) {
    const float* var_grid = (const float*)d_in[0];
    const int*   idxs     = (const int*)d_in[1];
    const float* means    = (const float*)d_in[2];
    const float* stds     = (const float*)d_in[3];
    const float* W1       = (const float*)d_in[4];
    const float* b1       = (const float*)d_in[5];
    const float* lnS      = (const float*)d_in[6];
    const float* lnO      = (const float*)d_in[7];
    const float* W2       = (const float*)d_in[8];
    const float* b2       = (const float*)d_in[9];
    float* out = (float*)d_out;

    char* ws = (char*)d_ws;
    unsigned short* bp1 = (unsigned short*)ws;               // 49152 B
    unsigned short* bp2 = (unsigned short*)(ws + 49152);     // 131072 B -> 180224
    float* latT = (float*)(ws + 180224);                     // 5768 B
    float* lonT = (float*)(ws + 186000);                     // 11520 B
    float* b1p  = (float*)(ws + 197520);                     // 1024 B
    float* K1   = (float*)(ws + 198544);                     // 1024 B
    float* K2   = (float*)(ws + 199568);                     // 1024 B (end 200592)

    prep_kernel<<<362, 256, 0, stream>>>(W1, W2, means, stds, b1, lnS, lnO, b2,
                                         bp1, bp2, latT, lonT, b1p, K1, K2);
    fused_kernel<<<NBLOCKS, 512, 0, stream>>>(var_grid, idxs, bp1, bp2, latT, lonT,
                                              b1p, K1, K2, out);
}